// Round 8
// baseline (358.973 us; speedup 1.0000x reference)
//
#include <hip/hip_runtime.h>
#include <cmath>

#define BB 64
#define NN 883
#define NP 896      // N padded to multiple of 64
#define EE 10
#define CC 66
#define KP 160      // A'/W' padded K: [0,66)=xs|W0+W1, [80,146)=-d*y|W1, rest 0
#define NT16 56     // NP/16 tiles
#define MB32 28     // NP/32 blocks
#define OTG 128
#define OTU 64

typedef __attribute__((ext_vector_type(8))) short bf16x8;
typedef __attribute__((ext_vector_type(4))) float f32x4;

__device__ __forceinline__ float sigmoidf_(float v) { return 1.f / (1.f + expf(-v)); }

// fp32 -> bf16 round-to-nearest-even
__device__ __forceinline__ unsigned short f2bf(float f) {
  unsigned int u = __float_as_uint(f);
  u = u + 0x7FFFu + ((u >> 16) & 1u);
  return (unsigned short)(u >> 16);
}
__device__ __forceinline__ float bf2f(unsigned short h) {
  return __uint_as_float(((unsigned int)h) << 16);
}
__device__ __forceinline__ unsigned int pk2(float a, float b) {
  return (unsigned int)f2bf(a) | ((unsigned int)f2bf(b) << 16);
}
__device__ __forceinline__ unsigned int pkrelu(float a, float b) {
  return (unsigned int)f2bf(fmaxf(a, 0.f)) | ((unsigned int)f2bf(fmaxf(b, 0.f)) << 16);
}
// split f32 -> bf16 hi + bf16 lo (residual); hi+lo reconstructs ~2^-18 relative
__device__ __forceinline__ void splitbf(float v, unsigned short& hi, unsigned short& lo) {
  hi = f2bf(v);
  lo = f2bf(v - bf2f(hi));
}

// Layouts:
//  Acat [n][b][k160] bf16
//  Wall_g/u [n(NP)][ks5][ot][col16][q4][8] bf16  (= W'[k=ks*32+q*8+j][o=ot*16+col])
//  wT   [k160][o][e32] bf16: slots 0..9 = w_hi, 10..19 = w_lo, 20..29 = w_hi
//  embb [n(NP)][e32] bf16:   slots 0..9 = e_hi, 10..19 = e_hi, 20..29 = e_lo
//    -> MFMA dot = e_hi*w_hi + e_hi*w_lo + e_lo*w_hi  (split-precision, ~f32)
//  biasg [n][128] f32, biasu [n][64] f32
//  zs   [b][n][64] f32 = z*state ;  rbuf [n][b][64] f32 = r
//  nv2  [b][ntile][slot][8] ; xsd2 [b][mb][ct][q][col][8]

// ---------------- K00: weight/emb transposes + bias (runs once, tiny) --------
__global__ __launch_bounds__(256) void k00_prep(
    const float* __restrict__ gwp, const float* __restrict__ gbp,
    const float* __restrict__ uwp, const float* __restrict__ ubp,
    const float* __restrict__ emb,
    unsigned short* __restrict__ wTg, unsigned short* __restrict__ wTu,
    unsigned short* __restrict__ embb,
    float* __restrict__ biasg, float* __restrict__ biasu) {
  int bid = blockIdx.x, t = threadIdx.x;
  if (bid < 80) {                       // gate wT: (k,o) elements, OT=128
    int idx = bid * 256 + t;            // k*128 + o
    int k = idx >> 7, o = idx & 127;
    unsigned short slots[32];
#pragma unroll
    for (int p = 0; p < 32; ++p) slots[p] = 0;
#pragma unroll
    for (int e = 0; e < EE; ++e) {
      float s = 0.f;
      if (k < CC)
        s = gwp[(((size_t)(e * 2 + 0) * CC + k)) * OTG + o] +
            gwp[(((size_t)(e * 2 + 1) * CC + k)) * OTG + o];
      else if (k >= 80 && k < 80 + CC)
        s = gwp[(((size_t)(e * 2 + 1) * CC + (k - 80))) * OTG + o];
      unsigned short hi, lo;
      splitbf(s, hi, lo);
      slots[e] = hi; slots[10 + e] = lo; slots[20 + e] = hi;
    }
    unsigned short* dst = &wTg[(size_t)idx * 32];
#pragma unroll
    for (int p = 0; p < 4; ++p) {
      unsigned int u0 = (unsigned int)slots[8 * p + 0] | ((unsigned int)slots[8 * p + 1] << 16);
      unsigned int u1 = (unsigned int)slots[8 * p + 2] | ((unsigned int)slots[8 * p + 3] << 16);
      unsigned int u2 = (unsigned int)slots[8 * p + 4] | ((unsigned int)slots[8 * p + 5] << 16);
      unsigned int u3 = (unsigned int)slots[8 * p + 6] | ((unsigned int)slots[8 * p + 7] << 16);
      *(uint4*)&dst[p * 8] = make_uint4(u0, u1, u2, u3);
    }
  } else if (bid < 120) {               // update wT: OT=64
    int idx = (bid - 80) * 256 + t;     // k*64 + o
    int k = idx >> 6, o = idx & 63;
    unsigned short slots[32];
#pragma unroll
    for (int p = 0; p < 32; ++p) slots[p] = 0;
#pragma unroll
    for (int e = 0; e < EE; ++e) {
      float s = 0.f;
      if (k < CC)
        s = uwp[(((size_t)(e * 2 + 0) * CC + k)) * OTU + o] +
            uwp[(((size_t)(e * 2 + 1) * CC + k)) * OTU + o];
      else if (k >= 80 && k < 80 + CC)
        s = uwp[(((size_t)(e * 2 + 1) * CC + (k - 80))) * OTU + o];
      unsigned short hi, lo;
      splitbf(s, hi, lo);
      slots[e] = hi; slots[10 + e] = lo; slots[20 + e] = hi;
    }
    unsigned short* dst = &wTu[(size_t)idx * 32];
#pragma unroll
    for (int p = 0; p < 4; ++p) {
      unsigned int u0 = (unsigned int)slots[8 * p + 0] | ((unsigned int)slots[8 * p + 1] << 16);
      unsigned int u1 = (unsigned int)slots[8 * p + 2] | ((unsigned int)slots[8 * p + 3] << 16);
      unsigned int u2 = (unsigned int)slots[8 * p + 4] | ((unsigned int)slots[8 * p + 5] << 16);
      unsigned int u3 = (unsigned int)slots[8 * p + 6] | ((unsigned int)slots[8 * p + 7] << 16);
      *(uint4*)&dst[p * 8] = make_uint4(u0, u1, u2, u3);
    }
  } else if (bid < 124) {               // embb
    int n = (bid - 120) * 256 + t;
    if (n >= NP) return;
    unsigned short slots[32];
#pragma unroll
    for (int p = 0; p < 32; ++p) slots[p] = 0;
#pragma unroll
    for (int e = 0; e < EE; ++e) {
      float v = (n < NN) ? emb[n * EE + e] : 0.f;
      unsigned short hi, lo;
      splitbf(v, hi, lo);
      slots[e] = hi; slots[10 + e] = hi; slots[20 + e] = lo;
    }
    unsigned short* dst = &embb[(size_t)n * 32];
#pragma unroll
    for (int p = 0; p < 4; ++p) {
      unsigned int u0 = (unsigned int)slots[8 * p + 0] | ((unsigned int)slots[8 * p + 1] << 16);
      unsigned int u1 = (unsigned int)slots[8 * p + 2] | ((unsigned int)slots[8 * p + 3] << 16);
      unsigned int u2 = (unsigned int)slots[8 * p + 4] | ((unsigned int)slots[8 * p + 5] << 16);
      unsigned int u3 = (unsigned int)slots[8 * p + 6] | ((unsigned int)slots[8 * p + 7] << 16);
      *(uint4*)&dst[p * 8] = make_uint4(u0, u1, u2, u3);
    }
  } else if (bid < 124 + 448) {         // biasg: n*128 + o over NP*128
    int idx = (bid - 124) * 256 + t;
    int n = idx >> 7, o = idx & 127;
    float s = 0.f;
    if (n < NN) {
#pragma unroll
      for (int e = 0; e < EE; ++e) s = fmaf(emb[n * EE + e], gbp[e * OTG + o], s);
    }
    biasg[idx] = s;
  } else {                              // biasu: n*64 + o over NP*64
    int idx = (bid - 572) * 256 + t;
    int n = idx >> 6, o = idx & 63;
    float s = 0.f;
    if (n < NN) {
#pragma unroll
      for (int e = 0; e < EE; ++e) s = fmaf(emb[n * EE + e], ubp[e * OTU + o], s);
    }
    biasu[idx] = s;
  }
}

// ---------------- K0: Wall[n] = emb[n] (x) wT  via split-precision MFMA over e ----
template<int OT>
__device__ __forceinline__ void k0_body(const unsigned short* __restrict__ wT,
                                        const unsigned short* __restrict__ embb,
                                        unsigned short* __restrict__ Wall,
                                        int ntile, int ot) {
  const int NOTT = OT / 16;
  int t = threadIdx.x, w = t >> 6, lane = t & 63, col = lane & 15, q = lane >> 4;
  int n0 = ntile * 16, o0 = ot * 16;
  bf16x8 af = *(const bf16x8*)&embb[(size_t)(n0 + col) * 32 + q * 8];
#pragma unroll
  for (int ks = 0; ks < 5; ++ks) {
    f32x4 c0, c1, c2, c3, c4, c5, c6, c7;
    f32x4 z = {0.f, 0.f, 0.f, 0.f};
    int kb = ks * 32 + w * 8;
#define K0MM(JJ, CV) { \
      bf16x8 bfr = *(const bf16x8*)&wT[((size_t)(kb + JJ) * OT + o0 + col) * 32 + q * 8]; \
      CV = __builtin_amdgcn_mfma_f32_16x16x32_bf16(af, bfr, z, 0, 0, 0); }
    K0MM(0, c0) K0MM(1, c1) K0MM(2, c2) K0MM(3, c3)
    K0MM(4, c4) K0MM(5, c5) K0MM(6, c6) K0MM(7, c7)
#undef K0MM
#pragma unroll
    for (int r = 0; r < 4; ++r) {
      unsigned int u0 = pk2(c0[r], c1[r]);
      unsigned int u1 = pk2(c2[r], c3[r]);
      unsigned int u2 = pk2(c4[r], c5[r]);
      unsigned int u3 = pk2(c6[r], c7[r]);
      size_t dst = (size_t)(n0 + q * 4 + r) * (160 * OT) +
                   ((((size_t)ks * NOTT + ot) * 16 + col) * 4 + w) * 8;
      *(uint4*)&Wall[dst] = make_uint4(u0, u1, u2, u3);
    }
  }
}

__global__ __launch_bounds__(256) void k0_wall(const unsigned short* __restrict__ wTg,
                                               const unsigned short* __restrict__ wTu,
                                               const unsigned short* __restrict__ embb,
                                               unsigned short* __restrict__ Wall_g,
                                               unsigned short* __restrict__ Wall_u) {
  int bid = blockIdx.x;
  if (bid < 56 * 8) {
    k0_body<OTG>(wTg, embb, Wall_g, bid >> 3, bid & 7);
  } else {
    int b2 = bid - 56 * 8;
    k0_body<OTU>(wTu, embb, Wall_u, b2 >> 2, b2 & 3);
  }
}

// ---------------- K1: concat + hyper-MLP + nodevec (8 threads per row) --------
// sp = state (phase A) or zs = z*state (phase B), both [b][n][64] f32.
// 256 thr = 32 rows x 8 chunks; chunk ch owns c = 2+8ch..2+8ch+7 (ch0 also x).
__global__ __launch_bounds__(256) void k1_hyper(
    const float* __restrict__ x, const float* __restrict__ sp,
    const float* __restrict__ emb,
    const float* __restrict__ tme, const float* __restrict__ day,
    const float* __restrict__ spd, const float* __restrict__ occ,
    const float* __restrict__ w1, const float* __restrict__ b1,
    const float* __restrict__ w2, const float* __restrict__ b2,
    const float* __restrict__ w3, const float* __restrict__ b3,
    unsigned short* __restrict__ Acat, unsigned short* __restrict__ nv2) {
  int t = threadIdx.x;
  int row = t >> 3, ch = t & 7;
  int rp = blockIdx.x * 32 + row;
  int b = rp / NP, n = rp - b * NP;
  bool valid = (n < NN);
  int bn = b * NN + n;

  __shared__ float ss[32][68];

  // ---- coalesced loads: chunk ch owns j in [8ch, 8ch+8) ----
  float4 sva = make_float4(0.f, 0.f, 0.f, 0.f);
  float4 svb = make_float4(0.f, 0.f, 0.f, 0.f);
  if (valid) {
    const float4* spv = (const float4*)&sp[(size_t)bn * 64 + ch * 8];
    sva = spv[0]; svb = spv[1];
  }
  float x0 = 0.f, x1 = 0.f;
  if (ch == 0 && valid) { x0 = x[bn * 2 + 0]; x1 = x[bn * 2 + 1]; }
  *(float4*)&ss[row][ch * 8 + 0] = sva;
  *(float4*)&ss[row][ch * 8 + 4] = svb;

  float sj[8] = {sva.x, sva.y, sva.z, sva.w, svb.x, svb.y, svb.z, svb.w};

  // ---- partial h1 over my 8 c's (+ x for ch0) ----
  const float4* w1v = (const float4*)w1;
  float h1[16];
#pragma unroll
  for (int j = 0; j < 16; ++j) h1[j] = 0.f;
  if (ch == 0) {
#pragma unroll
    for (int j = 0; j < 16; ++j) h1[j] = b1[j];
#pragma unroll
    for (int cc = 0; cc < 2; ++cc) {
      float xv = cc ? x1 : x0;
      float4 wa = w1v[cc * 4 + 0], wb = w1v[cc * 4 + 1];
      float4 wc = w1v[cc * 4 + 2], wd = w1v[cc * 4 + 3];
      h1[0] = fmaf(xv, wa.x, h1[0]);  h1[1] = fmaf(xv, wa.y, h1[1]);
      h1[2] = fmaf(xv, wa.z, h1[2]);  h1[3] = fmaf(xv, wa.w, h1[3]);
      h1[4] = fmaf(xv, wb.x, h1[4]);  h1[5] = fmaf(xv, wb.y, h1[5]);
      h1[6] = fmaf(xv, wb.z, h1[6]);  h1[7] = fmaf(xv, wb.w, h1[7]);
      h1[8] = fmaf(xv, wc.x, h1[8]);  h1[9] = fmaf(xv, wc.y, h1[9]);
      h1[10] = fmaf(xv, wc.z, h1[10]); h1[11] = fmaf(xv, wc.w, h1[11]);
      h1[12] = fmaf(xv, wd.x, h1[12]); h1[13] = fmaf(xv, wd.y, h1[13]);
      h1[14] = fmaf(xv, wd.z, h1[14]); h1[15] = fmaf(xv, wd.w, h1[15]);
    }
  }
#pragma unroll
  for (int l = 0; l < 8; ++l) {
    float xv = sj[l];
    int c = 2 + ch * 8 + l;
    float4 wa = w1v[c * 4 + 0], wb = w1v[c * 4 + 1];
    float4 wc = w1v[c * 4 + 2], wd = w1v[c * 4 + 3];
    h1[0] = fmaf(xv, wa.x, h1[0]);  h1[1] = fmaf(xv, wa.y, h1[1]);
    h1[2] = fmaf(xv, wa.z, h1[2]);  h1[3] = fmaf(xv, wa.w, h1[3]);
    h1[4] = fmaf(xv, wb.x, h1[4]);  h1[5] = fmaf(xv, wb.y, h1[5]);
    h1[6] = fmaf(xv, wb.z, h1[6]);  h1[7] = fmaf(xv, wb.w, h1[7]);
    h1[8] = fmaf(xv, wc.x, h1[8]);  h1[9] = fmaf(xv, wc.y, h1[9]);
    h1[10] = fmaf(xv, wc.z, h1[10]); h1[11] = fmaf(xv, wc.w, h1[11]);
    h1[12] = fmaf(xv, wd.x, h1[12]); h1[13] = fmaf(xv, wd.y, h1[13]);
    h1[14] = fmaf(xv, wd.z, h1[14]); h1[15] = fmaf(xv, wd.w, h1[15]);
  }
  // ---- reduce across 8 chunks (lanes row*8 + 0..7) ----
#pragma unroll
  for (int off = 1; off < 8; off <<= 1) {
#pragma unroll
    for (int j = 0; j < 16; ++j) h1[j] += __shfl_xor(h1[j], off);
  }

  __syncthreads();

  // ---- Acat xs-band writes: octet m = ch, plus m = 8+ch for ch<2 ----
  if (valid) {
    size_t arow = ((size_t)n * BB + b) * KP;
#pragma unroll
    for (int mi = 0; mi < 2; ++mi) {
      int m = mi ? (8 + ch) : ch;
      if (mi && ch >= 2) break;
      unsigned int u[4];
#pragma unroll
      for (int j = 0; j < 4; ++j) {
        int k0i = m * 8 + 2 * j;
        float v0, v1;
        if (m == 0 && j == 0) { v0 = x0; v1 = x1; }
        else {
          v0 = (k0i < CC) ? ss[row][k0i - 2] : 0.f;
          v1 = (k0i + 1 < CC) ? ss[row][k0i - 1] : 0.f;
        }
        u[j] = pk2(v0, v1);
      }
      *(uint4*)&Acat[arow + m * 8] = make_uint4(u[0], u[1], u[2], u[3]);
    }
  }

  // ---- nv: every lane computes h2; ch<5 handle e = 2ch, 2ch+1 ----
#pragma unroll
  for (int j = 0; j < 16; ++j) h1[j] = sigmoidf_(h1[j]);
  float h2[2];
#pragma unroll
  for (int j = 0; j < 2; ++j) {
    float s = b2[j];
#pragma unroll
    for (int i = 0; i < 16; ++i) s = fmaf(h1[i], w2[i * 2 + j], s);
    h2[j] = sigmoidf_(s);
  }
  size_t slot = ((size_t)(b * NT16 + (n >> 4)) * 32 + (n & 15) * 2) * 8;
  unsigned int word = 0;
  if (ch < 5 && valid) {
    int e0 = 2 * ch;
    float2 tm = *(const float2*)&tme[(size_t)bn * EE + e0];
    float2 dy = *(const float2*)&day[(size_t)bn * EE + e0];
    float2 sd = *(const float2*)&spd[(size_t)bn * EE + e0];
    float2 oc = *(const float2*)&occ[(size_t)bn * EE + e0];
    float2 em = *(const float2*)&emb[(size_t)n * EE + e0];
    float f0 = b3[e0]     + h2[0] * w3[e0]     + h2[1] * w3[EE + e0];
    float f1 = b3[e0 + 1] + h2[0] * w3[e0 + 1] + h2[1] * w3[EE + e0 + 1];
    float nv0 = tanhf(em.x * tm.x * dy.x * sd.x * oc.x * f0);
    float nv1 = tanhf(em.y * tm.y * dy.y * sd.y * oc.y * f1);
    word = pk2(nv0, nv1);
  }
  *(unsigned int*)&nv2[slot + ch * 2] = word;   // 8 words = full 16-short slot
}

// XCD-aware decode for the 896-block (nt=14, b=64) kernels.
__device__ __forceinline__ void decode_ntb(int id, int& nt, int& b) {
  int rest = id >> 3;
  nt = rest % 14;
  b = (id & 7) + 8 * (rest / 14);
}

// ---------------- K2: degree via MFMA (4-deep prefetch) + xsd2 build ----------------
__global__ __launch_bounds__(256) void k2_deg(const unsigned short* __restrict__ nv2,
                                              const unsigned short* __restrict__ Acat,
                                              float* __restrict__ d_g,
                                              unsigned short* __restrict__ xsd2) {
  int nt, b;
  decode_ntb(blockIdx.x, nt, b);
  int t = threadIdx.x, wid = t >> 6, lane = t & 63;
  int col = lane & 15, q = lane >> 4;
  __shared__ float tile[64][67];
  __shared__ float d_s[64];

  const unsigned short* nvb = nv2 + (size_t)b * NT16 * 32 * 8;
  bf16x8 zf = {0, 0, 0, 0, 0, 0, 0, 0};
  bf16x8 anv = zf;
  if (q < 2) anv = *(const bf16x8*)&nvb[((size_t)(nt * 4 + wid) * 32 + col * 2 + q) * 8];

#define NVLD(MT) (*(const bf16x8*)&nvb[((size_t)(MT) * 32 + col * 2 + q) * 8])
  float rs[4] = {0.f, 0.f, 0.f, 0.f};
  bf16x8 p0 = zf, p1 = zf, p2 = zf, p3 = zf;
  if (q < 2) { p0 = NVLD(0); p1 = NVLD(1); p2 = NVLD(2); p3 = NVLD(3); }
  for (int mt = 0; mt < NT16; mt += 4) {
    f32x4 z = {0.f, 0.f, 0.f, 0.f};
    f32x4 g0 = __builtin_amdgcn_mfma_f32_16x16x32_bf16(anv, p0, z, 0, 0, 0);
    if (q < 2 && mt + 4 < NT16) p0 = NVLD(mt + 4);
    f32x4 g1 = __builtin_amdgcn_mfma_f32_16x16x32_bf16(anv, p1, z, 0, 0, 0);
    if (q < 2 && mt + 5 < NT16) p1 = NVLD(mt + 5);
    f32x4 g2 = __builtin_amdgcn_mfma_f32_16x16x32_bf16(anv, p2, z, 0, 0, 0);
    if (q < 2 && mt + 6 < NT16) p2 = NVLD(mt + 6);
    f32x4 g3 = __builtin_amdgcn_mfma_f32_16x16x32_bf16(anv, p3, z, 0, 0, 0);
    if (q < 2 && mt + 7 < NT16) p3 = NVLD(mt + 7);
#pragma unroll
    for (int r = 0; r < 4; ++r)
      rs[r] += fmaxf(g0[r], 0.f) + fmaxf(g1[r], 0.f) + fmaxf(g2[r], 0.f) + fmaxf(g3[r], 0.f);
  }
#undef NVLD
#pragma unroll
  for (int off = 1; off < 16; off <<= 1) {
#pragma unroll
    for (int r = 0; r < 4; ++r) rs[r] += __shfl_xor(rs[r], off);
  }
  if (col == 0) {
#pragma unroll
    for (int r = 0; r < 4; ++r) {
      int n = nt * 64 + wid * 16 + q * 4 + r;
      float dv = (n < NN) ? rsqrtf(rs[r]) : 0.f;
      d_g[b * NP + n] = dv;
      d_s[wid * 16 + q * 4 + r] = dv;
    }
  }
  __syncthreads();

  int mb = nt * 64;
  // vectorized tile fill: 64 rows x 9 octets (uint4 = 8 bf16 per load)
  for (int idx = t; idx < 64 * 9; idx += 256) {
    int ml = idx / 9, oc8 = idx - ml * 9;
    int m = mb + ml;
    uint4 v = make_uint4(0, 0, 0, 0);
    if (m < NN) v = *(const uint4*)&Acat[((size_t)m * BB + b) * KP + oc8 * 8];
    float ds = d_s[ml];
    unsigned int ww[4] = {v.x, v.y, v.z, v.w};
#pragma unroll
    for (int p = 0; p < 4; ++p) {
      int c = oc8 * 8 + 2 * p;
      if (c < CC)     tile[ml][c]     = bf2f((unsigned short)(ww[p] & 0xffffu)) * ds;
      if (c + 1 < CC) tile[ml][c + 1] = bf2f((unsigned short)(ww[p] >> 16)) * ds;
    }
  }
  __syncthreads();
  for (int idx = t; idx < 2 * 5 * 4 * 16; idx += 256) {
    int colw = idx & 15;
    int qw = (idx >> 4) & 3;
    int ctw = (idx >> 6) % 5;
    int mbbl = idx / (16 * 4 * 5);
    unsigned int o[4];
#pragma unroll
    for (int jj = 0; jj < 4; ++jj) {
      int ml = mbbl * 32 + qw * 8 + jj * 2;
      int c = ctw * 16 + colw;
      float v0 = (c < CC) ? tile[ml][c] : 0.f;
      float v1 = (c < CC) ? tile[ml + 1][c] : 0.f;
      o[jj] = (unsigned int)f2bf(v0) | ((unsigned int)f2bf(v1) << 16);
    }
    size_t dst = (((((size_t)b * MB32 + (nt * 2 + mbbl)) * 5 + ctw) * 4 + qw) * 16 + colw) * 8;
    *(uint4*)&xsd2[dst] = make_uint4(o[0], o[1], o[2], o[3]);
  }
}

// ---------------- K3: Acat[n][b][80+c] = -d[n] * sum_m relu(nv.nv)[n,m] * xsd[m,c] ----
__global__ __launch_bounds__(256) void k3_agg(const unsigned short* __restrict__ nv2,
                                              const float* __restrict__ d_g,
                                              const unsigned short* __restrict__ xsd2,
                                              unsigned short* __restrict__ Acat) {
  int nt, b;
  decode_ntb(blockIdx.x, nt, b);
  int t = threadIdx.x;
  int wid = t >> 6, lane = t & 63, col = lane & 15, q = lane >> 4;
  int n16 = nt * 64 + wid * 16;

  const unsigned short* nvb = nv2 + (size_t)b * NT16 * 32 * 8;
  const unsigned short* xb = xsd2 + (size_t)b * MB32 * 5 * 4 * 16 * 8;

  __shared__ float os[64][81];

  bf16x8 zf = {0, 0, 0, 0, 0, 0, 0, 0};
  bf16x8 anv = zf;
  if (q < 2) anv = *(const bf16x8*)&nvb[((size_t)(nt * 4 + wid) * 32 + col * 2 + q) * 8];

  f32x4 acc[5];
#pragma unroll
  for (int ct = 0; ct < 5; ++ct) acc[ct] = (f32x4){0.f, 0.f, 0.f, 0.f};

  int base = ((q & 1) << 5) + col;
  bool hi = (q >= 2);

  for (int i = 0; i < MB32; ++i) {
    bf16x8 b0 = zf, b1 = zf;
    if (q < 2) {
      b0 = *(const bf16x8*)&nvb[((size_t)(i * 2) * 32 + col * 2 + q) * 8];
      b1 = *(const bf16x8*)&nvb[((size_t)(i * 2 + 1) * 32 + col * 2 + q) * 8];
    }
    bf16x8 xf[5];
#pragma unroll
    for (int ct = 0; ct < 5; ++ct)
      xf[ct] = *(const bf16x8*)&xb[((((size_t)i * 5 + ct) * 4 + q) * 16 + col) * 8];

    f32x4 z = {0.f, 0.f, 0.f, 0.f};
    f32x4 g0 = __builtin_amdgcn_mfma_f32_16x16x32_bf16(b0, anv, z, 0, 0, 0);
    f32x4 g1 = __builtin_amdgcn_mfma_f32_16x16x32_bf16(b1, anv, z, 0, 0, 0);
    unsigned int p00 = pkrelu(g0[0], g0[1]), p01 = pkrelu(g0[2], g0[3]);
    unsigned int p10 = pkrelu(g1[0], g1[1]), p11 = pkrelu(g1[2], g1[3]);
    unsigned int s00 = (unsigned int)__shfl((int)p00, base);
    unsigned int s01 = (unsigned int)__shfl((int)p01, base);
    unsigned int s02 = (unsigned int)__shfl((int)p00, base + 16);
    unsigned int s03 = (unsigned int)__shfl((int)p01, base + 16);
    unsigned int s10 = (unsigned int)__shfl((int)p10, base);
    unsigned int s11 = (unsigned int)__shfl((int)p11, base);
    unsigned int s12 = (unsigned int)__shfl((int)p10, base + 16);
    unsigned int s13 = (unsigned int)__shfl((int)p11, base + 16);
    union { unsigned int u[4]; bf16x8 v; } cv;
    cv.u[0] = hi ? s10 : s00;
    cv.u[1] = hi ? s11 : s01;
    cv.u[2] = hi ? s12 : s02;
    cv.u[3] = hi ? s13 : s03;

#pragma unroll
    for (int ct = 0; ct < 5; ++ct)
      acc[ct] = __builtin_amdgcn_mfma_f32_16x16x32_bf16(cv.v, xf[ct], acc[ct], 0, 0, 0);
  }

  float dn[4];
#pragma unroll
  for (int r = 0; r < 4; ++r) dn[r] = d_g[b * NP + n16 + q * 4 + r];
  // stage to LDS, then vectorized Acat writes (uint4 = 8 bf16)
#pragma unroll
  for (int ct = 0; ct < 5; ++ct) {
#pragma unroll
    for (int r = 0; r < 4; ++r)
      os[wid * 16 + q * 4 + r][ct * 16 + col] = -(acc[ct][r] * dn[r]);
  }
  __syncthreads();
  for (int idx = t; idx < 64 * 10; idx += 256) {
    int rowl = idx / 10, oc8 = idx - rowl * 10;
    int n = nt * 64 + rowl;
    if (n < NN) {
      const float* p = &os[rowl][oc8 * 8];
      unsigned int u0 = pk2(p[0], p[1]);
      unsigned int u1 = pk2(p[2], p[3]);
      unsigned int u2 = pk2(p[4], p[5]);
      unsigned int u3 = pk2(p[6], p[7]);
      *(uint4*)&Acat[((size_t)n * BB + b) * KP + 80 + oc8 * 8] = make_uint4(u0, u1, u2, u3);
    }
  }
}

// ---------------- K4: pure streaming GEMM, no LDS, no barrier ----------------
// grid (NN), 256 thr = 4 waves (wave = 16 b-rows, all OT columns).
// Bias added f32 in epilogue from precomputed buffer.
template<int OT, bool GATE>
__global__ __launch_bounds__(256) void k4b_gemm(
    const unsigned short* __restrict__ Wall,
    const unsigned short* __restrict__ Acat,
    const float* __restrict__ bias_all,
    const float* __restrict__ state,
    float* __restrict__ zs, float* __restrict__ rbuf,
    float* __restrict__ out) {
  constexpr int NOTT = OT / 16;
  int n = blockIdx.x, t = threadIdx.x;
  int wid = t >> 6, lane = t & 63, col = lane & 15, q = lane >> 4;

  // A-frags: contiguous 20.5KB slice for this n
  const unsigned short* Ab = &Acat[((size_t)n * BB + wid * 16 + col) * KP];
  bf16x8 af[5];
#pragma unroll
  for (int ks = 0; ks < 5; ++ks) af[ks] = *(const bf16x8*)&Ab[ks * 32 + q * 8];

  // epilogue prefetch (hide latency under MFMA stream)
  float pre_s[16], pre_r[16];
#pragma unroll
  for (int i = 0; i < 16; ++i) { pre_s[i] = 0.f; pre_r[i] = 0.f; }
#pragma unroll
  for (int ot = 0; ot < 4; ++ot) {
    int o = ot * 16 + col;
#pragma unroll
    for (int r = 0; r < 4; ++r) {
      int bb = wid * 16 + q * 4 + r;
      pre_s[ot * 4 + r] = state[((size_t)bb * NN + n) * 64 + o];
      if (!GATE) pre_r[ot * 4 + r] = rbuf[((size_t)n * BB + bb) * 64 + o];
    }
  }

  // W-frags + MFMA (W reads broadcast across the 4 waves -> L1)
  const unsigned short* Wn = &Wall[(size_t)n * (160 * OT)];
  f32x4 acc[NOTT];
#pragma unroll
  for (int ot = 0; ot < NOTT; ++ot) acc[ot] = (f32x4){0.f, 0.f, 0.f, 0.f};
#pragma unroll
  for (int ks = 0; ks < 5; ++ks) {
#pragma unroll
    for (int ot = 0; ot < NOTT; ++ot) {
      bf16x8 bfr = *(const bf16x8*)&Wn[((((size_t)ks * NOTT + ot) * 16 + col) * 4 + q) * 8];
      acc[ot] = __builtin_amdgcn_mfma_f32_16x16x32_bf16(af[ks], bfr, acc[ot], 0, 0, 0);
    }
  }

  // epilogue
#pragma unroll
  for (int ot = 0; ot < NOTT; ++ot) {
    int o = ot * 16 + col;
    float bia = bias_all[(size_t)n * OT + o];
#pragma unroll
    for (int r = 0; r < 4; ++r) {
      int bb = wid * 16 + q * 4 + r;
      float v = acc[ot][r] + bia;
      if (GATE) {
        if (ot < 4) {           // z-half: write z*state (b-major, for k1 phase B)
          float z = sigmoidf_(v);
          zs[((size_t)bb * NN + n) * 64 + o] = z * pre_s[ot * 4 + r];
        } else {                // r-half: write r (n-major, for k4u)
          float rv = sigmoidf_(v);
          rbuf[((size_t)n * BB + bb) * 64 + (o - 64)] = rv;
        }
      } else {
        float hc = tanhf(v);
        float rr = pre_r[ot * 4 + r];
        float st = pre_s[ot * 4 + r];
        out[((size_t)bb * NN + n) * 64 + o] = fmaf(rr, st - hc, hc);
      }
    }
  }
}

extern "C" void kernel_launch(void* const* d_in, const int* in_sizes, int n_in,
                              void* d_out, int out_size, void* d_ws, size_t ws_size,
                              hipStream_t stream) {
  const float* x     = (const float*)d_in[0];
  const float* state = (const float*)d_in[1];
  const float* emb   = (const float*)d_in[2];
  const float* tme   = (const float*)d_in[3];
  const float* day   = (const float*)d_in[4];
  const float* spd   = (const float*)d_in[5];
  const float* occ   = (const float*)d_in[6];
  const float* gwp   = (const float*)d_in[7];
  const float* gbp   = (const float*)d_in[8];
  const float* gw1   = (const float*)d_in[9];
  const float* gb1   = (const float*)d_in[10];
  const float* gw2   = (const float*)d_in[11];
  const float* gb2   = (const float*)d_in[12];
  const float* gw3   = (const float*)d_in[13];
  const float* gb3   = (const float*)d_in[14];
  const float* uwp   = (const float*)d_in[15];
  const float* ubp   = (const float*)d_in[16];
  const float* uw1   = (const float*)d_in[17];
  const float* ub1   = (const float*)d_in[18];
  const float* uw2   = (const float*)d_in[19];
  const float* ub2   = (const float*)d_in[20];
  const float* uw3   = (const float*)d_in[21];
  const float* ub3   = (const float*)d_in[22];

  char* w = (char*)d_ws;
  unsigned short* Acat   = (unsigned short*)w;  w += (size_t)NN * BB * KP * 2;          // 18.1 MB
  unsigned short* nv2    = (unsigned short*)w;  w += (size_t)BB * NT16 * 32 * 8 * 2;    // 1.84 MB
  unsigned short* xsd2   = (unsigned short*)w;  w += (size_t)BB * MB32 * 5 * 4 * 16 * 8 * 2;  // 9.2 MB
  float* d_g             = (float*)w;           w += (size_t)BB * NP * 4;
  float* zs              = (float*)w;           w += (size_t)BB * NN * 64 * 4;          // 14.5 MB
  float* rbuf            = (float*)w;           w += (size_t)NN * BB * 64 * 4;          // 14.5 MB
  unsigned short* Wall_g = (unsigned short*)w;  w += (size_t)NP * 160 * OTG * 2;        // 36.7 MB
  unsigned short* Wall_u = (unsigned short*)w;  w += (size_t)NP * 160 * OTU * 2;        // 18.4 MB
  unsigned short* wTg    = (unsigned short*)w;  w += (size_t)160 * OTG * 32 * 2;        // 1.3 MB
  unsigned short* wTu    = (unsigned short*)w;  w += (size_t)160 * OTU * 32 * 2;        // 0.66 MB
  unsigned short* embb   = (unsigned short*)w;  w += (size_t)NP * 32 * 2;
  float* biasg           = (float*)w;           w += (size_t)NP * OTG * 4;              // 0.46 MB
  float* biasu           = (float*)w;           w += (size_t)NP * OTU * 4;              // 0.23 MB

  dim3 b256(256);
  dim3 gK00(796);                 // 80 gwT + 40 uwT + 4 embb + 448 biasg + 224 biasu
  dim3 gK0(56 * 8 + 56 * 4);      // 672: Wall_g then Wall_u
  dim3 gK1((BB * NP) / 32);       // 1792
  dim3 gK2(14 * BB);              // 896, XCD-swizzled decode inside
  dim3 gK4(NN);

  k00_prep<<<gK00, b256, 0, stream>>>(gwp, gbp, uwp, ubp, emb, wTg, wTu, embb,
                                      biasg, biasu);
  k0_wall<<<gK0, b256, 0, stream>>>(wTg, wTu, embb, Wall_g, Wall_u);

  // phase A (gate)
  k1_hyper<<<gK1, b256, 0, stream>>>(x, state, emb, tme, day, spd, occ,
                                     gw1, gb1, gw2, gb2, gw3, gb3, Acat, nv2);
  k2_deg<<<gK2, b256, 0, stream>>>(nv2, Acat, d_g, xsd2);
  k3_agg<<<gK2, b256, 0, stream>>>(nv2, d_g, xsd2, Acat);
  k4b_gemm<OTG, true><<<gK4, b256, 0, stream>>>(Wall_g, Acat, biasg, state,
                                                zs, rbuf, nullptr);
  // phase B (update)
  k1_hyper<<<gK1, b256, 0, stream>>>(x, zs, emb, tme, day, spd, occ,
                                     uw1, ub1, uw2, ub2, uw3, ub3, Acat, nv2);
  k2_deg<<<gK2, b256, 0, stream>>>(nv2, Acat, d_g, xsd2);
  k3_agg<<<gK2, b256, 0, stream>>>(nv2, d_g, xsd2, Acat);
  k4b_gemm<OTU, false><<<gK4, b256, 0, stream>>>(Wall_u, Acat, biasu, state,
                                                 zs, rbuf, (float*)d_out);
}

// Round 9
// 326.395 us; speedup vs baseline: 1.0998x; 1.0998x over previous
//
#include <hip/hip_runtime.h>
#include <cmath>

#define BB 64
#define NN 883
#define NP 896      // N padded to multiple of 64
#define EE 10
#define CC 66
#define KP 160      // A'/W' padded K: [0,66)=xs|W0+W1, [80,146)=-d*y|W1, rest 0
#define NT16 56     // NP/16 tiles
#define MB32 28     // NP/32 blocks
#define OTG 128
#define OTU 64

typedef __attribute__((ext_vector_type(8))) short bf16x8;
typedef __attribute__((ext_vector_type(4))) float f32x4;

__device__ __forceinline__ float sigmoidf_(float v) { return 1.f / (1.f + expf(-v)); }

// fp32 -> bf16 round-to-nearest-even
__device__ __forceinline__ unsigned short f2bf(float f) {
  unsigned int u = __float_as_uint(f);
  u = u + 0x7FFFu + ((u >> 16) & 1u);
  return (unsigned short)(u >> 16);
}
__device__ __forceinline__ float bf2f(unsigned short h) {
  return __uint_as_float(((unsigned int)h) << 16);
}
__device__ __forceinline__ unsigned int pk2(float a, float b) {
  return (unsigned int)f2bf(a) | ((unsigned int)f2bf(b) << 16);
}
__device__ __forceinline__ unsigned int pkrelu(float a, float b) {
  return (unsigned int)f2bf(fmaxf(a, 0.f)) | ((unsigned int)f2bf(fmaxf(b, 0.f)) << 16);
}
// split f32 -> bf16 hi + bf16 lo (residual); hi+lo reconstructs ~2^-18 relative
__device__ __forceinline__ void splitbf(float v, unsigned short& hi, unsigned short& lo) {
  hi = f2bf(v);
  lo = f2bf(v - bf2f(hi));
}

// Layouts:
//  Acat [n][b][k160] bf16
//  Wall_g/u [n(NP)][ks5][ot][col16][q4][8] bf16  (= W'[k=ks*32+q*8+j][o=ot*16+col])
//  wT   [k160][o][e32] bf16: slots 0..9 = w_hi, 10..19 = w_lo, 20..29 = w_hi
//  embb [n(NP)][e32] bf16:   slots 0..9 = e_hi, 10..19 = e_hi, 20..29 = e_lo
//    -> MFMA dot = e_hi*w_hi + e_hi*w_lo + e_lo*w_hi  (split-precision, ~f32)
//  biasg [n][128] f32, biasu [n][64] f32
//  zs   [b][n][64] f32 = z*state ;  rbuf [n][b][64] f32 = r
//  nv2  [b][ntile][slot][8] ; xsd2 [b][mb][ct][q][col][8]

// ---------------- K00: weight/emb transposes + bias (runs once, tiny) --------
__global__ __launch_bounds__(256) void k00_prep(
    const float* __restrict__ gwp, const float* __restrict__ gbp,
    const float* __restrict__ uwp, const float* __restrict__ ubp,
    const float* __restrict__ emb,
    unsigned short* __restrict__ wTg, unsigned short* __restrict__ wTu,
    unsigned short* __restrict__ embb,
    float* __restrict__ biasg, float* __restrict__ biasu) {
  int bid = blockIdx.x, t = threadIdx.x;
  if (bid < 80) {                       // gate wT: (k,o) elements, OT=128
    int idx = bid * 256 + t;            // k*128 + o
    int k = idx >> 7, o = idx & 127;
    unsigned short slots[32];
#pragma unroll
    for (int p = 0; p < 32; ++p) slots[p] = 0;
#pragma unroll
    for (int e = 0; e < EE; ++e) {
      float s = 0.f;
      if (k < CC)
        s = gwp[(((size_t)(e * 2 + 0) * CC + k)) * OTG + o] +
            gwp[(((size_t)(e * 2 + 1) * CC + k)) * OTG + o];
      else if (k >= 80 && k < 80 + CC)
        s = gwp[(((size_t)(e * 2 + 1) * CC + (k - 80))) * OTG + o];
      unsigned short hi, lo;
      splitbf(s, hi, lo);
      slots[e] = hi; slots[10 + e] = lo; slots[20 + e] = hi;
    }
    unsigned short* dst = &wTg[(size_t)idx * 32];
#pragma unroll
    for (int p = 0; p < 4; ++p) {
      unsigned int u0 = (unsigned int)slots[8 * p + 0] | ((unsigned int)slots[8 * p + 1] << 16);
      unsigned int u1 = (unsigned int)slots[8 * p + 2] | ((unsigned int)slots[8 * p + 3] << 16);
      unsigned int u2 = (unsigned int)slots[8 * p + 4] | ((unsigned int)slots[8 * p + 5] << 16);
      unsigned int u3 = (unsigned int)slots[8 * p + 6] | ((unsigned int)slots[8 * p + 7] << 16);
      *(uint4*)&dst[p * 8] = make_uint4(u0, u1, u2, u3);
    }
  } else if (bid < 120) {               // update wT: OT=64
    int idx = (bid - 80) * 256 + t;     // k*64 + o
    int k = idx >> 6, o = idx & 63;
    unsigned short slots[32];
#pragma unroll
    for (int p = 0; p < 32; ++p) slots[p] = 0;
#pragma unroll
    for (int e = 0; e < EE; ++e) {
      float s = 0.f;
      if (k < CC)
        s = uwp[(((size_t)(e * 2 + 0) * CC + k)) * OTU + o] +
            uwp[(((size_t)(e * 2 + 1) * CC + k)) * OTU + o];
      else if (k >= 80 && k < 80 + CC)
        s = uwp[(((size_t)(e * 2 + 1) * CC + (k - 80))) * OTU + o];
      unsigned short hi, lo;
      splitbf(s, hi, lo);
      slots[e] = hi; slots[10 + e] = lo; slots[20 + e] = hi;
    }
    unsigned short* dst = &wTu[(size_t)idx * 32];
#pragma unroll
    for (int p = 0; p < 4; ++p) {
      unsigned int u0 = (unsigned int)slots[8 * p + 0] | ((unsigned int)slots[8 * p + 1] << 16);
      unsigned int u1 = (unsigned int)slots[8 * p + 2] | ((unsigned int)slots[8 * p + 3] << 16);
      unsigned int u2 = (unsigned int)slots[8 * p + 4] | ((unsigned int)slots[8 * p + 5] << 16);
      unsigned int u3 = (unsigned int)slots[8 * p + 6] | ((unsigned int)slots[8 * p + 7] << 16);
      *(uint4*)&dst[p * 8] = make_uint4(u0, u1, u2, u3);
    }
  } else if (bid < 124) {               // embb
    int n = (bid - 120) * 256 + t;
    if (n >= NP) return;
    unsigned short slots[32];
#pragma unroll
    for (int p = 0; p < 32; ++p) slots[p] = 0;
#pragma unroll
    for (int e = 0; e < EE; ++e) {
      float v = (n < NN) ? emb[n * EE + e] : 0.f;
      unsigned short hi, lo;
      splitbf(v, hi, lo);
      slots[e] = hi; slots[10 + e] = hi; slots[20 + e] = lo;
    }
    unsigned short* dst = &embb[(size_t)n * 32];
#pragma unroll
    for (int p = 0; p < 4; ++p) {
      unsigned int u0 = (unsigned int)slots[8 * p + 0] | ((unsigned int)slots[8 * p + 1] << 16);
      unsigned int u1 = (unsigned int)slots[8 * p + 2] | ((unsigned int)slots[8 * p + 3] << 16);
      unsigned int u2 = (unsigned int)slots[8 * p + 4] | ((unsigned int)slots[8 * p + 5] << 16);
      unsigned int u3 = (unsigned int)slots[8 * p + 6] | ((unsigned int)slots[8 * p + 7] << 16);
      *(uint4*)&dst[p * 8] = make_uint4(u0, u1, u2, u3);
    }
  } else if (bid < 124 + 448) {         // biasg: n*128 + o over NP*128
    int idx = (bid - 124) * 256 + t;
    int n = idx >> 7, o = idx & 127;
    float s = 0.f;
    if (n < NN) {
#pragma unroll
      for (int e = 0; e < EE; ++e) s = fmaf(emb[n * EE + e], gbp[e * OTG + o], s);
    }
    biasg[idx] = s;
  } else {                              // biasu: n*64 + o over NP*64
    int idx = (bid - 572) * 256 + t;
    int n = idx >> 6, o = idx & 63;
    float s = 0.f;
    if (n < NN) {
#pragma unroll
      for (int e = 0; e < EE; ++e) s = fmaf(emb[n * EE + e], ubp[e * OTU + o], s);
    }
    biasu[idx] = s;
  }
}

// ---------------- K0: Wall[n] = emb[n] (x) wT  via split-precision MFMA over e ----
template<int OT>
__device__ __forceinline__ void k0_body(const unsigned short* __restrict__ wT,
                                        const unsigned short* __restrict__ embb,
                                        unsigned short* __restrict__ Wall,
                                        int ntile, int ot) {
  const int NOTT = OT / 16;
  int t = threadIdx.x, w = t >> 6, lane = t & 63, col = lane & 15, q = lane >> 4;
  int n0 = ntile * 16, o0 = ot * 16;
  bf16x8 af = *(const bf16x8*)&embb[(size_t)(n0 + col) * 32 + q * 8];
#pragma unroll
  for (int ks = 0; ks < 5; ++ks) {
    f32x4 c0, c1, c2, c3, c4, c5, c6, c7;
    f32x4 z = {0.f, 0.f, 0.f, 0.f};
    int kb = ks * 32 + w * 8;
#define K0MM(JJ, CV) { \
      bf16x8 bfr = *(const bf16x8*)&wT[((size_t)(kb + JJ) * OT + o0 + col) * 32 + q * 8]; \
      CV = __builtin_amdgcn_mfma_f32_16x16x32_bf16(af, bfr, z, 0, 0, 0); }
    K0MM(0, c0) K0MM(1, c1) K0MM(2, c2) K0MM(3, c3)
    K0MM(4, c4) K0MM(5, c5) K0MM(6, c6) K0MM(7, c7)
#undef K0MM
#pragma unroll
    for (int r = 0; r < 4; ++r) {
      unsigned int u0 = pk2(c0[r], c1[r]);
      unsigned int u1 = pk2(c2[r], c3[r]);
      unsigned int u2 = pk2(c4[r], c5[r]);
      unsigned int u3 = pk2(c6[r], c7[r]);
      size_t dst = (size_t)(n0 + q * 4 + r) * (160 * OT) +
                   ((((size_t)ks * NOTT + ot) * 16 + col) * 4 + w) * 8;
      *(uint4*)&Wall[dst] = make_uint4(u0, u1, u2, u3);
    }
  }
}

__global__ __launch_bounds__(256) void k0_wall(const unsigned short* __restrict__ wTg,
                                               const unsigned short* __restrict__ wTu,
                                               const unsigned short* __restrict__ embb,
                                               unsigned short* __restrict__ Wall_g,
                                               unsigned short* __restrict__ Wall_u) {
  int bid = blockIdx.x;
  if (bid < 56 * 8) {
    k0_body<OTG>(wTg, embb, Wall_g, bid >> 3, bid & 7);
  } else {
    int b2 = bid - 56 * 8;
    k0_body<OTU>(wTu, embb, Wall_u, b2 >> 2, b2 & 3);
  }
}

// ---------------- K1: concat + hyper-MLP + nodevec (8 threads per row) --------
// sp = state (phase A) or zs = z*state (phase B), both [b][n][64] f32.
// 256 thr = 32 rows x 8 chunks; chunk ch owns c = 2+8ch..2+8ch+7 (ch0 also x).
__global__ __launch_bounds__(256) void k1_hyper(
    const float* __restrict__ x, const float* __restrict__ sp,
    const float* __restrict__ emb,
    const float* __restrict__ tme, const float* __restrict__ day,
    const float* __restrict__ spd, const float* __restrict__ occ,
    const float* __restrict__ w1, const float* __restrict__ b1,
    const float* __restrict__ w2, const float* __restrict__ b2,
    const float* __restrict__ w3, const float* __restrict__ b3,
    unsigned short* __restrict__ Acat, unsigned short* __restrict__ nv2) {
  int t = threadIdx.x;
  int row = t >> 3, ch = t & 7;
  int rp = blockIdx.x * 32 + row;
  int b = rp / NP, n = rp - b * NP;
  bool valid = (n < NN);
  int bn = b * NN + n;

  __shared__ float ss[32][68];

  // ---- coalesced loads: chunk ch owns j in [8ch, 8ch+8) ----
  float4 sva = make_float4(0.f, 0.f, 0.f, 0.f);
  float4 svb = make_float4(0.f, 0.f, 0.f, 0.f);
  if (valid) {
    const float4* spv = (const float4*)&sp[(size_t)bn * 64 + ch * 8];
    sva = spv[0]; svb = spv[1];
  }
  float x0 = 0.f, x1 = 0.f;
  if (ch == 0 && valid) { x0 = x[bn * 2 + 0]; x1 = x[bn * 2 + 1]; }
  *(float4*)&ss[row][ch * 8 + 0] = sva;
  *(float4*)&ss[row][ch * 8 + 4] = svb;

  float sj[8] = {sva.x, sva.y, sva.z, sva.w, svb.x, svb.y, svb.z, svb.w};

  // ---- partial h1 over my 8 c's (+ x for ch0) ----
  const float4* w1v = (const float4*)w1;
  float h1[16];
#pragma unroll
  for (int j = 0; j < 16; ++j) h1[j] = 0.f;
  if (ch == 0) {
#pragma unroll
    for (int j = 0; j < 16; ++j) h1[j] = b1[j];
#pragma unroll
    for (int cc = 0; cc < 2; ++cc) {
      float xv = cc ? x1 : x0;
      float4 wa = w1v[cc * 4 + 0], wb = w1v[cc * 4 + 1];
      float4 wc = w1v[cc * 4 + 2], wd = w1v[cc * 4 + 3];
      h1[0] = fmaf(xv, wa.x, h1[0]);  h1[1] = fmaf(xv, wa.y, h1[1]);
      h1[2] = fmaf(xv, wa.z, h1[2]);  h1[3] = fmaf(xv, wa.w, h1[3]);
      h1[4] = fmaf(xv, wb.x, h1[4]);  h1[5] = fmaf(xv, wb.y, h1[5]);
      h1[6] = fmaf(xv, wb.z, h1[6]);  h1[7] = fmaf(xv, wb.w, h1[7]);
      h1[8] = fmaf(xv, wc.x, h1[8]);  h1[9] = fmaf(xv, wc.y, h1[9]);
      h1[10] = fmaf(xv, wc.z, h1[10]); h1[11] = fmaf(xv, wc.w, h1[11]);
      h1[12] = fmaf(xv, wd.x, h1[12]); h1[13] = fmaf(xv, wd.y, h1[13]);
      h1[14] = fmaf(xv, wd.z, h1[14]); h1[15] = fmaf(xv, wd.w, h1[15]);
    }
  }
#pragma unroll
  for (int l = 0; l < 8; ++l) {
    float xv = sj[l];
    int c = 2 + ch * 8 + l;
    float4 wa = w1v[c * 4 + 0], wb = w1v[c * 4 + 1];
    float4 wc = w1v[c * 4 + 2], wd = w1v[c * 4 + 3];
    h1[0] = fmaf(xv, wa.x, h1[0]);  h1[1] = fmaf(xv, wa.y, h1[1]);
    h1[2] = fmaf(xv, wa.z, h1[2]);  h1[3] = fmaf(xv, wa.w, h1[3]);
    h1[4] = fmaf(xv, wb.x, h1[4]);  h1[5] = fmaf(xv, wb.y, h1[5]);
    h1[6] = fmaf(xv, wb.z, h1[6]);  h1[7] = fmaf(xv, wb.w, h1[7]);
    h1[8] = fmaf(xv, wc.x, h1[8]);  h1[9] = fmaf(xv, wc.y, h1[9]);
    h1[10] = fmaf(xv, wc.z, h1[10]); h1[11] = fmaf(xv, wc.w, h1[11]);
    h1[12] = fmaf(xv, wd.x, h1[12]); h1[13] = fmaf(xv, wd.y, h1[13]);
    h1[14] = fmaf(xv, wd.z, h1[14]); h1[15] = fmaf(xv, wd.w, h1[15]);
  }
  // ---- reduce across 8 chunks (lanes row*8 + 0..7) ----
#pragma unroll
  for (int off = 1; off < 8; off <<= 1) {
#pragma unroll
    for (int j = 0; j < 16; ++j) h1[j] += __shfl_xor(h1[j], off);
  }

  __syncthreads();

  // ---- Acat xs-band writes: octet m = ch, plus m = 8+ch for ch<2 ----
  if (valid) {
    size_t arow = ((size_t)n * BB + b) * KP;
#pragma unroll
    for (int mi = 0; mi < 2; ++mi) {
      int m = mi ? (8 + ch) : ch;
      if (mi && ch >= 2) break;
      unsigned int u[4];
#pragma unroll
      for (int j = 0; j < 4; ++j) {
        int k0i = m * 8 + 2 * j;
        float v0, v1;
        if (m == 0 && j == 0) { v0 = x0; v1 = x1; }
        else {
          v0 = (k0i < CC) ? ss[row][k0i - 2] : 0.f;
          v1 = (k0i + 1 < CC) ? ss[row][k0i - 1] : 0.f;
        }
        u[j] = pk2(v0, v1);
      }
      *(uint4*)&Acat[arow + m * 8] = make_uint4(u[0], u[1], u[2], u[3]);
    }
  }

  // ---- nv: every lane computes h2; ch<5 handle e = 2ch, 2ch+1 ----
#pragma unroll
  for (int j = 0; j < 16; ++j) h1[j] = sigmoidf_(h1[j]);
  float h2[2];
#pragma unroll
  for (int j = 0; j < 2; ++j) {
    float s = b2[j];
#pragma unroll
    for (int i = 0; i < 16; ++i) s = fmaf(h1[i], w2[i * 2 + j], s);
    h2[j] = sigmoidf_(s);
  }
  size_t slot = ((size_t)(b * NT16 + (n >> 4)) * 32 + (n & 15) * 2) * 8;
  unsigned int word = 0;
  if (ch < 5 && valid) {
    int e0 = 2 * ch;
    float2 tm = *(const float2*)&tme[(size_t)bn * EE + e0];
    float2 dy = *(const float2*)&day[(size_t)bn * EE + e0];
    float2 sd = *(const float2*)&spd[(size_t)bn * EE + e0];
    float2 oc = *(const float2*)&occ[(size_t)bn * EE + e0];
    float2 em = *(const float2*)&emb[(size_t)n * EE + e0];
    float f0 = b3[e0]     + h2[0] * w3[e0]     + h2[1] * w3[EE + e0];
    float f1 = b3[e0 + 1] + h2[0] * w3[e0 + 1] + h2[1] * w3[EE + e0 + 1];
    float nv0 = tanhf(em.x * tm.x * dy.x * sd.x * oc.x * f0);
    float nv1 = tanhf(em.y * tm.y * dy.y * sd.y * oc.y * f1);
    word = pk2(nv0, nv1);
  }
  *(unsigned int*)&nv2[slot + ch * 2] = word;   // 8 words = full 16-short slot
}

// XCD-aware decode for the 896-block (nt=14, b=64) kernels.
__device__ __forceinline__ void decode_ntb(int id, int& nt, int& b) {
  int rest = id >> 3;
  nt = rest % 14;
  b = (id & 7) + 8 * (rest / 14);
}

// ---------------- K2: degree via MFMA + fused rsqrt + xsd2 build ----------------
__global__ __launch_bounds__(256) void k2_deg(const unsigned short* __restrict__ nv2,
                                              const unsigned short* __restrict__ Acat,
                                              float* __restrict__ d_g,
                                              unsigned short* __restrict__ xsd2) {
  int nt, b;
  decode_ntb(blockIdx.x, nt, b);
  int t = threadIdx.x, wid = t >> 6, lane = t & 63;
  int col = lane & 15, q = lane >> 4;
  __shared__ float tile[64][67];
  __shared__ float d_s[64];

  const unsigned short* nvb = nv2 + (size_t)b * NT16 * 32 * 8;
  bf16x8 zf = {0, 0, 0, 0, 0, 0, 0, 0};
  bf16x8 anv = zf;
  if (q < 2) anv = *(const bf16x8*)&nvb[((size_t)(nt * 4 + wid) * 32 + col * 2 + q) * 8];

  float rs[4] = {0.f, 0.f, 0.f, 0.f};
  bf16x8 cur = zf, nxt = zf;
  if (q < 2) cur = *(const bf16x8*)&nvb[((size_t)0 * 32 + col * 2 + q) * 8];
  for (int mt = 0; mt < NT16; ++mt) {
    if (q < 2 && mt + 1 < NT16)
      nxt = *(const bf16x8*)&nvb[((size_t)(mt + 1) * 32 + col * 2 + q) * 8];
    f32x4 z = {0.f, 0.f, 0.f, 0.f};
    f32x4 g = __builtin_amdgcn_mfma_f32_16x16x32_bf16(anv, cur, z, 0, 0, 0);
#pragma unroll
    for (int r = 0; r < 4; ++r) rs[r] += fmaxf(g[r], 0.f);
    cur = nxt;
  }
#pragma unroll
  for (int off = 1; off < 16; off <<= 1) {
#pragma unroll
    for (int r = 0; r < 4; ++r) rs[r] += __shfl_xor(rs[r], off);
  }
  if (col == 0) {
#pragma unroll
    for (int r = 0; r < 4; ++r) {
      int n = nt * 64 + wid * 16 + q * 4 + r;
      float dv = (n < NN) ? rsqrtf(rs[r]) : 0.f;
      d_g[b * NP + n] = dv;
      d_s[wid * 16 + q * 4 + r] = dv;
    }
  }
  __syncthreads();

  int mb = nt * 64;
  // vectorized tile fill: 64 rows x 9 octets (uint4 = 8 bf16 per load)
  for (int idx = t; idx < 64 * 9; idx += 256) {
    int ml = idx / 9, oc8 = idx - ml * 9;
    int m = mb + ml;
    uint4 v = make_uint4(0, 0, 0, 0);
    if (m < NN) v = *(const uint4*)&Acat[((size_t)m * BB + b) * KP + oc8 * 8];
    float ds = d_s[ml];
    unsigned int ww[4] = {v.x, v.y, v.z, v.w};
#pragma unroll
    for (int p = 0; p < 4; ++p) {
      int c = oc8 * 8 + 2 * p;
      if (c < CC)     tile[ml][c]     = bf2f((unsigned short)(ww[p] & 0xffffu)) * ds;
      if (c + 1 < CC) tile[ml][c + 1] = bf2f((unsigned short)(ww[p] >> 16)) * ds;
    }
  }
  __syncthreads();
  for (int idx = t; idx < 2 * 5 * 4 * 16; idx += 256) {
    int colw = idx & 15;
    int qw = (idx >> 4) & 3;
    int ctw = (idx >> 6) % 5;
    int mbbl = idx / (16 * 4 * 5);
    unsigned int o[4];
#pragma unroll
    for (int jj = 0; jj < 4; ++jj) {
      int ml = mbbl * 32 + qw * 8 + jj * 2;
      int c = ctw * 16 + colw;
      float v0 = (c < CC) ? tile[ml][c] : 0.f;
      float v1 = (c < CC) ? tile[ml + 1][c] : 0.f;
      o[jj] = (unsigned int)f2bf(v0) | ((unsigned int)f2bf(v1) << 16);
    }
    size_t dst = (((((size_t)b * MB32 + (nt * 2 + mbbl)) * 5 + ctw) * 4 + qw) * 16 + colw) * 8;
    *(uint4*)&xsd2[dst] = make_uint4(o[0], o[1], o[2], o[3]);
  }
}

// ---------------- K3: Acat[n][b][80+c] = -d[n] * sum_m relu(nv.nv)[n,m] * xsd[m,c] ----
__global__ __launch_bounds__(256) void k3_agg(const unsigned short* __restrict__ nv2,
                                              const float* __restrict__ d_g,
                                              const unsigned short* __restrict__ xsd2,
                                              unsigned short* __restrict__ Acat) {
  int nt, b;
  decode_ntb(blockIdx.x, nt, b);
  int t = threadIdx.x;
  int wid = t >> 6, lane = t & 63, col = lane & 15, q = lane >> 4;
  int n16 = nt * 64 + wid * 16;

  const unsigned short* nvb = nv2 + (size_t)b * NT16 * 32 * 8;
  const unsigned short* xb = xsd2 + (size_t)b * MB32 * 5 * 4 * 16 * 8;

  __shared__ float os[64][81];

  bf16x8 zf = {0, 0, 0, 0, 0, 0, 0, 0};
  bf16x8 anv = zf;
  if (q < 2) anv = *(const bf16x8*)&nvb[((size_t)(nt * 4 + wid) * 32 + col * 2 + q) * 8];

  f32x4 acc[5];
#pragma unroll
  for (int ct = 0; ct < 5; ++ct) acc[ct] = (f32x4){0.f, 0.f, 0.f, 0.f};

  int base = ((q & 1) << 5) + col;
  bool hi = (q >= 2);

  for (int i = 0; i < MB32; ++i) {
    bf16x8 b0 = zf, b1 = zf;
    if (q < 2) {
      b0 = *(const bf16x8*)&nvb[((size_t)(i * 2) * 32 + col * 2 + q) * 8];
      b1 = *(const bf16x8*)&nvb[((size_t)(i * 2 + 1) * 32 + col * 2 + q) * 8];
    }
    bf16x8 xf[5];
#pragma unroll
    for (int ct = 0; ct < 5; ++ct)
      xf[ct] = *(const bf16x8*)&xb[((((size_t)i * 5 + ct) * 4 + q) * 16 + col) * 8];

    f32x4 z = {0.f, 0.f, 0.f, 0.f};
    f32x4 g0 = __builtin_amdgcn_mfma_f32_16x16x32_bf16(b0, anv, z, 0, 0, 0);
    f32x4 g1 = __builtin_amdgcn_mfma_f32_16x16x32_bf16(b1, anv, z, 0, 0, 0);
    unsigned int p00 = pkrelu(g0[0], g0[1]), p01 = pkrelu(g0[2], g0[3]);
    unsigned int p10 = pkrelu(g1[0], g1[1]), p11 = pkrelu(g1[2], g1[3]);
    unsigned int s00 = (unsigned int)__shfl((int)p00, base);
    unsigned int s01 = (unsigned int)__shfl((int)p01, base);
    unsigned int s02 = (unsigned int)__shfl((int)p00, base + 16);
    unsigned int s03 = (unsigned int)__shfl((int)p01, base + 16);
    unsigned int s10 = (unsigned int)__shfl((int)p10, base);
    unsigned int s11 = (unsigned int)__shfl((int)p11, base);
    unsigned int s12 = (unsigned int)__shfl((int)p10, base + 16);
    unsigned int s13 = (unsigned int)__shfl((int)p11, base + 16);
    union { unsigned int u[4]; bf16x8 v; } cv;
    cv.u[0] = hi ? s10 : s00;
    cv.u[1] = hi ? s11 : s01;
    cv.u[2] = hi ? s12 : s02;
    cv.u[3] = hi ? s13 : s03;

#pragma unroll
    for (int ct = 0; ct < 5; ++ct)
      acc[ct] = __builtin_amdgcn_mfma_f32_16x16x32_bf16(cv.v, xf[ct], acc[ct], 0, 0, 0);
  }

  float dn[4];
#pragma unroll
  for (int r = 0; r < 4; ++r) dn[r] = d_g[b * NP + n16 + q * 4 + r];
  // stage to LDS, then vectorized Acat writes (uint4 = 8 bf16)
#pragma unroll
  for (int ct = 0; ct < 5; ++ct) {
#pragma unroll
    for (int r = 0; r < 4; ++r)
      os[wid * 16 + q * 4 + r][ct * 16 + col] = -(acc[ct][r] * dn[r]);
  }
  __syncthreads();
  for (int idx = t; idx < 64 * 10; idx += 256) {
    int rowl = idx / 10, oc8 = idx - rowl * 10;
    int n = nt * 64 + rowl;
    if (n < NN) {
      const float* p = &os[rowl][oc8 * 8];
      unsigned int u0 = pk2(p[0], p[1]);
      unsigned int u1 = pk2(p[2], p[3]);
      unsigned int u2 = pk2(p[4], p[5]);
      unsigned int u3 = pk2(p[6], p[7]);
      *(uint4*)&Acat[((size_t)n * BB + b) * KP + 80 + oc8 * 8] = make_uint4(u0, u1, u2, u3);
    }
  }
}

// ---------------- K4: pure streaming GEMM, no LDS, no barrier ----------------
// grid (NN), 256 thr = 4 waves (wave = 16 b-rows, all OT columns).
// Bias added f32 in epilogue from precomputed buffer.
template<int OT, bool GATE>
__global__ __launch_bounds__(256) void k4b_gemm(
    const unsigned short* __restrict__ Wall,
    const unsigned short* __restrict__ Acat,
    const float* __restrict__ bias_all,
    const float* __restrict__ state,
    float* __restrict__ zs, float* __restrict__ rbuf,
    float* __restrict__ out) {
  constexpr int NOTT = OT / 16;
  int n = blockIdx.x, t = threadIdx.x;
  int wid = t >> 6, lane = t & 63, col = lane & 15, q = lane >> 4;

  // A-frags: contiguous 20.5KB slice for this n
  const unsigned short* Ab = &Acat[((size_t)n * BB + wid * 16 + col) * KP];
  bf16x8 af[5];
#pragma unroll
  for (int ks = 0; ks < 5; ++ks) af[ks] = *(const bf16x8*)&Ab[ks * 32 + q * 8];

  // epilogue prefetch (hide latency under MFMA stream)
  float pre_s[16], pre_r[16];
#pragma unroll
  for (int i = 0; i < 16; ++i) { pre_s[i] = 0.f; pre_r[i] = 0.f; }
#pragma unroll
  for (int ot = 0; ot < 4; ++ot) {
    int o = ot * 16 + col;
#pragma unroll
    for (int r = 0; r < 4; ++r) {
      int bb = wid * 16 + q * 4 + r;
      pre_s[ot * 4 + r] = state[((size_t)bb * NN + n) * 64 + o];
      if (!GATE) pre_r[ot * 4 + r] = rbuf[((size_t)n * BB + bb) * 64 + o];
    }
  }

  // W-frags + MFMA (W reads broadcast across the 4 waves -> L1)
  const unsigned short* Wn = &Wall[(size_t)n * (160 * OT)];
  f32x4 acc[NOTT];
#pragma unroll
  for (int ot = 0; ot < NOTT; ++ot) acc[ot] = (f32x4){0.f, 0.f, 0.f, 0.f};
#pragma unroll
  for (int ks = 0; ks < 5; ++ks) {
#pragma unroll
    for (int ot = 0; ot < NOTT; ++ot) {
      bf16x8 bfr = *(const bf16x8*)&Wn[((((size_t)ks * NOTT + ot) * 16 + col) * 4 + q) * 8];
      acc[ot] = __builtin_amdgcn_mfma_f32_16x16x32_bf16(af[ks], bfr, acc[ot], 0, 0, 0);
    }
  }

  // epilogue
#pragma unroll
  for (int ot = 0; ot < NOTT; ++ot) {
    int o = ot * 16 + col;
    float bia = bias_all[(size_t)n * OT + o];
#pragma unroll
    for (int r = 0; r < 4; ++r) {
      int bb = wid * 16 + q * 4 + r;
      float v = acc[ot][r] + bia;
      if (GATE) {
        if (ot < 4) {           // z-half: write z*state (b-major, for k1 phase B)
          float z = sigmoidf_(v);
          zs[((size_t)bb * NN + n) * 64 + o] = z * pre_s[ot * 4 + r];
        } else {                // r-half: write r (n-major, for k4u)
          float rv = sigmoidf_(v);
          rbuf[((size_t)n * BB + bb) * 64 + (o - 64)] = rv;
        }
      } else {
        float hc = tanhf(v);
        float rr = pre_r[ot * 4 + r];
        float st = pre_s[ot * 4 + r];
        out[((size_t)bb * NN + n) * 64 + o] = fmaf(rr, st - hc, hc);
      }
    }
  }
}

extern "C" void kernel_launch(void* const* d_in, const int* in_sizes, int n_in,
                              void* d_out, int out_size, void* d_ws, size_t ws_size,
                              hipStream_t stream) {
  const float* x     = (const float*)d_in[0];
  const float* state = (const float*)d_in[1];
  const float* emb   = (const float*)d_in[2];
  const float* tme   = (const float*)d_in[3];
  const float* day   = (const float*)d_in[4];
  const float* spd   = (const float*)d_in[5];
  const float* occ   = (const float*)d_in[6];
  const float* gwp   = (const float*)d_in[7];
  const float* gbp   = (const float*)d_in[8];
  const float* gw1   = (const float*)d_in[9];
  const float* gb1   = (const float*)d_in[10];
  const float* gw2   = (const float*)d_in[11];
  const float* gb2   = (const float*)d_in[12];
  const float* gw3   = (const float*)d_in[13];
  const float* gb3   = (const float*)d_in[14];
  const float* uwp   = (const float*)d_in[15];
  const float* ubp   = (const float*)d_in[16];
  const float* uw1   = (const float*)d_in[17];
  const float* ub1   = (const float*)d_in[18];
  const float* uw2   = (const float*)d_in[19];
  const float* ub2   = (const float*)d_in[20];
  const float* uw3   = (const float*)d_in[21];
  const float* ub3   = (const float*)d_in[22];

  char* w = (char*)d_ws;
  unsigned short* Acat   = (unsigned short*)w;  w += (size_t)NN * BB * KP * 2;          // 18.1 MB
  unsigned short* nv2    = (unsigned short*)w;  w += (size_t)BB * NT16 * 32 * 8 * 2;    // 1.84 MB
  unsigned short* xsd2   = (unsigned short*)w;  w += (size_t)BB * MB32 * 5 * 4 * 16 * 8 * 2;  // 9.2 MB
  float* d_g             = (float*)w;           w += (size_t)BB * NP * 4;
  float* zs              = (float*)w;           w += (size_t)BB * NN * 64 * 4;          // 14.5 MB
  float* rbuf            = (float*)w;           w += (size_t)NN * BB * 64 * 4;          // 14.5 MB
  unsigned short* Wall_g = (unsigned short*)w;  w += (size_t)NP * 160 * OTG * 2;        // 36.7 MB
  unsigned short* Wall_u = (unsigned short*)w;  w += (size_t)NP * 160 * OTU * 2;        // 18.4 MB
  unsigned short* wTg    = (unsigned short*)w;  w += (size_t)160 * OTG * 32 * 2;        // 1.3 MB
  unsigned short* wTu    = (unsigned short*)w;  w += (size_t)160 * OTU * 32 * 2;        // 0.66 MB
  unsigned short* embb   = (unsigned short*)w;  w += (size_t)NP * 32 * 2;
  float* biasg           = (float*)w;           w += (size_t)NP * OTG * 4;              // 0.46 MB
  float* biasu           = (float*)w;           w += (size_t)NP * OTU * 4;              // 0.23 MB

  dim3 b256(256);
  dim3 gK00(796);                 // 80 gwT + 40 uwT + 4 embb + 448 biasg + 224 biasu
  dim3 gK0(56 * 8 + 56 * 4);      // 672: Wall_g then Wall_u
  dim3 gK1((BB * NP) / 32);       // 1792
  dim3 gK2(14 * BB);              // 896, XCD-swizzled decode inside
  dim3 gK4(NN);

  k00_prep<<<gK00, b256, 0, stream>>>(gwp, gbp, uwp, ubp, emb, wTg, wTu, embb,
                                      biasg, biasu);
  k0_wall<<<gK0, b256, 0, stream>>>(wTg, wTu, embb, Wall_g, Wall_u);

  // phase A (gate)
  k1_hyper<<<gK1, b256, 0, stream>>>(x, state, emb, tme, day, spd, occ,
                                     gw1, gb1, gw2, gb2, gw3, gb3, Acat, nv2);
  k2_deg<<<gK2, b256, 0, stream>>>(nv2, Acat, d_g, xsd2);
  k3_agg<<<gK2, b256, 0, stream>>>(nv2, d_g, xsd2, Acat);
  k4b_gemm<OTG, true><<<gK4, b256, 0, stream>>>(Wall_g, Acat, biasg, state,
                                                zs, rbuf, nullptr);
  // phase B (update)
  k1_hyper<<<gK1, b256, 0, stream>>>(x, zs, emb, tme, day, spd, occ,
                                     uw1, ub1, uw2, ub2, uw3, ub3, Acat, nv2);
  k2_deg<<<gK2, b256, 0, stream>>>(nv2, Acat, d_g, xsd2);
  k3_agg<<<gK2, b256, 0, stream>>>(nv2, d_g, xsd2, Acat);
  k4b_gemm<OTU, false><<<gK4, b256, 0, stream>>>(Wall_u, Acat, biasu, state,
                                                 zs, rbuf, (float*)d_out);
}